// Round 7
// baseline (560.444 us; speedup 1.0000x reference)
//
#include <hip/hip_runtime.h>
#include <hip/hip_cooperative_groups.h>
#include <math.h>

namespace cg = cooperative_groups;

#define D 64
#define B 64
#define NPB 512      // nodes per block-chunk in attention phase
#define NSLOT 4
#define SCAN_BS 1024

__device__ __forceinline__ unsigned encf(float x) {
  unsigned u = __float_as_uint(x);
  return (u & 0x80000000u) ? ~u : (u | 0x80000000u);
}
__device__ __forceinline__ float decf(unsigned e) {
  return (e & 0x80000000u) ? __uint_as_float(e ^ 0x80000000u) : __uint_as_float(~e);
}
__device__ __forceinline__ float sigm(float x) { return 1.0f / (1.0f + expf(-x)); }

// ---------------- CSR build + gather (scatter-mean of efeat onto dst nodes) --

__global__ void k_deg(const int* __restrict__ edge_dst, int* __restrict__ deg, int E) {
  int i = blockIdx.x * blockDim.x + threadIdx.x;
  if (i < E) atomicAdd(&deg[edge_dst[i]], 1);
}

__global__ void k_scan1(const int* __restrict__ deg, int* __restrict__ row_start,
                        int* __restrict__ blocksum, int N) {
  __shared__ int sm[SCAN_BS];
  int t = threadIdx.x;
  int base = blockIdx.x * SCAN_BS;
  int v = (base + t < N) ? deg[base + t] : 0;
  sm[t] = v;
  __syncthreads();
  for (int ofs = 1; ofs < SCAN_BS; ofs <<= 1) {
    int add = (t >= ofs) ? sm[t - ofs] : 0;
    __syncthreads();
    sm[t] += add;
    __syncthreads();
  }
  if (base + t < N) row_start[base + t] = sm[t] - v;   // exclusive
  if (t == SCAN_BS - 1) blocksum[blockIdx.x] = sm[t];
}

__global__ void k_scan2(int* __restrict__ blocksum, int nb) {
  __shared__ int sm[128];
  int t = threadIdx.x;
  int v = (t < nb) ? blocksum[t] : 0;
  sm[t] = v;
  __syncthreads();
  for (int ofs = 1; ofs < 128; ofs <<= 1) {
    int add = (t >= ofs) ? sm[t - ofs] : 0;
    __syncthreads();
    sm[t] += add;
    __syncthreads();
  }
  if (t < nb) blocksum[t] = sm[t] - v;   // exclusive, in place
}

__global__ void k_scan3(int* __restrict__ row_start, const int* __restrict__ blocksum,
                        int* __restrict__ cursor, int N) {
  int n = blockIdx.x * blockDim.x + threadIdx.x;
  if (n < N) {
    int v = row_start[n] + blocksum[n / SCAN_BS];
    row_start[n] = v;
    cursor[n] = v;
  }
}

__global__ void k_fill(const int* __restrict__ edge_dst, int* __restrict__ cursor,
                       int* __restrict__ csr, int E) {
  int e = blockIdx.x * blockDim.x + threadIdx.x;
  if (e < E) {
    int dst = edge_dst[e];
    int idx = atomicAdd(&cursor[dst], 1);
    csr[idx] = e;
  }
}

// one 16-lane group per node; lane = 4 dims (float4). Unroll 16 -> 64
// outstanding 256B row reads per wave.
__global__ void k_gather(const float* __restrict__ efeat, const int* __restrict__ csr,
                         const int* __restrict__ row_start, const int* __restrict__ deg,
                         float* __restrict__ edge_agg, int N) {
  int grp = (blockIdx.x * blockDim.x + threadIdx.x) >> 4;
  int l16 = threadIdx.x & 15;
  if (grp >= N) return;
  int base = row_start[grp];
  int dg = deg[grp];
  float4 acc = make_float4(0.f, 0.f, 0.f, 0.f);
  for (int i = 0; i < dg; i += 16) {
    int idx[16];
    #pragma unroll
    for (int j = 0; j < 16; ++j) {
      int k = i + j;
      idx[j] = csr[base + (k < dg ? k : dg - 1)];   // clamped: stays in row
    }
    #pragma unroll
    for (int j = 0; j < 16; ++j) {
      float4 v = *(const float4*)(efeat + (size_t)idx[j] * D + l16 * 4);
      bool ok = (i + j < dg);
      acc.x += ok ? v.x : 0.0f;
      acc.y += ok ? v.y : 0.0f;
      acc.z += ok ? v.z : 0.0f;
      acc.w += ok ? v.w : 0.0f;
    }
  }
  float inv = 1.0f / fmaxf((float)dg, 1.0f);
  acc.x *= inv; acc.y *= inv; acc.z *= inv; acc.w *= inv;
  *(float4*)(edge_agg + (size_t)grp * D + l16 * 4) = acc;
}

// ---------------- Cooperative Set2Set mega-kernel (both sides) ---------------
// grid (nchunks, 2), 256 threads. Per iteration:
//   blocks bx<B: LSTM for graph bx of their side  -> grid.sync
//   all blocks: one-pass attention over their NPB-node chunk -> grid.sync
// After 3 iterations: blocks (bx<B, side 0) compute the MLP.

__global__ __launch_bounds__(256, 2)
void k_s2s(const float* __restrict__ feat, const float* __restrict__ edge_agg,
           const int* __restrict__ gid,
           float* __restrict__ h2g, float* __restrict__ c2g,
           float* __restrict__ s2g, float* __restrict__ r2g,
           unsigned* __restrict__ m2g, float* __restrict__ off2g,
           const float* __restrict__ nWih, const float* __restrict__ nWhh,
           const float* __restrict__ nbih, const float* __restrict__ nbhh,
           const float* __restrict__ eWih, const float* __restrict__ eWhh,
           const float* __restrict__ ebih, const float* __restrict__ ebhh,
           const float* __restrict__ W1, const float* __restrict__ b1,
           const float* __restrict__ W2, const float* __restrict__ b2,
           const float* __restrict__ W3, const float* __restrict__ b3,
           float* __restrict__ out, int N) {
  cg::grid_group gg = cg::this_grid();

  const int side = blockIdx.y;
  const int bx = blockIdx.x;
  const int tid = threadIdx.x;

  const float* F   = side ? edge_agg : feat;
  const float* Wih = side ? eWih : nWih;
  const float* Whh = side ? eWhh : nWhh;
  const float* bih = side ? ebih : nbih;
  const float* bhh = side ? ebhh : nbhh;
  float* h     = h2g + side * B * D;
  float* c     = c2g + side * B * D;
  float* s_buf = s2g + side * B;
  float* r_buf = r2g + side * B * D;
  unsigned* m_enc = m2g + side * B;
  float* off   = off2g + side * B;

  __shared__ float r_lds[16 * NSLOT * D];   // 16KB
  __shared__ float s_lds[16 * NSLOT];
  __shared__ float m_lds[16 * NSLOT];
  __shared__ float h_lds[NSLOT * D];
  __shared__ float o_lds[NSLOT];
  __shared__ int used[NSLOT];
  __shared__ int sg_first;
  __shared__ float lq[2 * D];               // LSTM: [h | r/s]; first D doubles as h for Whh
  __shared__ float lsg[4 * D];

  const int base = bx * NPB;
  const int grp = tid >> 4;
  const int d4  = tid & 15;

  for (int it = 0; it < 3; ++it) {
    // ---------------- LSTM phase (blocks bx < B) ----------------
    if (bx < B) {
      const int b = bx, j = tid;
      if (j < D) {
        lq[j] = h[b * D + j];
      } else if (j < 2 * D) {
        lq[j] = (it == 0) ? 0.0f : (r_buf[b * D + (j - D)] / s_buf[b]);
      }
      __syncthreads();
      float acc = bih[j] + bhh[j];
      const float* wr = Wih + (size_t)j * (2 * D);
      #pragma unroll 8
      for (int k = 0; k < 2 * D; ++k) acc += lq[k] * wr[k];
      const float* wr2 = Whh + (size_t)j * D;
      #pragma unroll 8
      for (int k = 0; k < D; ++k) acc += lq[k] * wr2[k];
      lsg[j] = acc;
      __syncthreads();
      if (j < D) {
        float ig = sigm(lsg[j]);
        float fg = sigm(lsg[D + j]);
        float gGate = tanhf(lsg[2 * D + j]);
        float og = sigm(lsg[3 * D + j]);
        float cn = fg * c[b * D + j] + ig * gGate;
        c[b * D + j] = cn;
        h[b * D + j] = og * tanhf(cn);
        r_buf[b * D + j] = 0.0f;
      }
      if (j == D) s_buf[b] = 0.0f;
      if (j == D + 1) {
        off[b] = (it == 0) ? 0.0f : decf(m_enc[b]);  // exact: const offset cancels
        m_enc[b] = 0u;
      }
      __syncthreads();
    }
    gg.sync();

    // ---------------- Attention phase (all blocks, one chunk each) ----------
    for (int i = tid; i < 16 * NSLOT * D; i += 256) r_lds[i] = 0.0f;
    if (tid < 16 * NSLOT) { s_lds[tid] = 0.0f; m_lds[tid] = -3.4e38f; }
    if (tid < NSLOT) used[tid] = 0;
    if (tid == 0) sg_first = gid[base];
    __syncthreads();
    const int gfirst = sg_first;
    {
      int slot = tid >> 6, dim = tid & 63;
      int g = gfirst + slot;
      if (g < B) {
        h_lds[tid] = h[g * D + dim];
        if (dim == 0) o_lds[slot] = off[g];
      }
    }
    __syncthreads();

    float4 acc = make_float4(0.f, 0.f, 0.f, 0.f);
    float sum_ex = 0.0f;
    float local_max = -3.4e38f;
    int cur_g = -1;

    for (int itn = 0; itn < NPB / 32; ++itn) {
      int n0 = base + itn * 32 + grp;
      int n1 = n0 + 16;
      bool ok0 = n0 < N, ok1 = n1 < N;
      int g0 = ok0 ? gid[n0] : -1;
      int g1 = ok1 ? gid[n1] : -1;
      float4 f0 = make_float4(0,0,0,0), f1 = make_float4(0,0,0,0);
      float dot0 = 0.f, dot1 = 0.f, ex0 = 0.f, ex1 = 0.f;
      if (ok0) {
        f0 = *(const float4*)(F + (size_t)n0 * D + d4 * 4);
        int s0 = g0 - gfirst;
        float4 hv = (s0 >= 0 && s0 < NSLOT) ? *(const float4*)&h_lds[(s0 << 6) + (d4 << 2)]
                                            : *(const float4*)(h + (size_t)g0 * D + d4 * 4);
        dot0 = f0.x * hv.x + f0.y * hv.y + f0.z * hv.z + f0.w * hv.w;
      }
      if (ok1) {
        f1 = *(const float4*)(F + (size_t)n1 * D + d4 * 4);
        int s1 = g1 - gfirst;
        float4 hv = (s1 >= 0 && s1 < NSLOT) ? *(const float4*)&h_lds[(s1 << 6) + (d4 << 2)]
                                            : *(const float4*)(h + (size_t)g1 * D + d4 * 4);
        dot1 = f1.x * hv.x + f1.y * hv.y + f1.z * hv.z + f1.w * hv.w;
      }
      dot0 += __shfl_xor(dot0, 1); dot1 += __shfl_xor(dot1, 1);
      dot0 += __shfl_xor(dot0, 2); dot1 += __shfl_xor(dot1, 2);
      dot0 += __shfl_xor(dot0, 4); dot1 += __shfl_xor(dot1, 4);
      dot0 += __shfl_xor(dot0, 8); dot1 += __shfl_xor(dot1, 8);
      if (ok0) {
        int s0 = g0 - gfirst;
        ex0 = expf(dot0 - ((s0 >= 0 && s0 < NSLOT) ? o_lds[s0] : off[g0]));
      }
      if (ok1) {
        int s1 = g1 - gfirst;
        ex1 = expf(dot1 - ((s1 >= 0 && s1 < NSLOT) ? o_lds[s1] : off[g1]));
      }

      #pragma unroll
      for (int pair = 0; pair < 2; ++pair) {
        bool ok = pair ? ok1 : ok0;
        int g = pair ? g1 : g0;
        float ex = pair ? ex1 : ex0;
        float dt = pair ? dot1 : dot0;
        float4 f = pair ? f1 : f0;
        if (!ok) continue;
        if (g != cur_g) {
          if (cur_g >= 0) {
            int slot = cur_g - gfirst;
            if (slot >= 0 && slot < NSLOT) {
              float4* p = (float4*)&r_lds[((grp * NSLOT + slot) << 6) + (d4 << 2)];
              float4 v = *p;
              v.x += acc.x; v.y += acc.y; v.z += acc.z; v.w += acc.w;
              *p = v;
              if (d4 == 0) {
                s_lds[grp * NSLOT + slot] += sum_ex;
                m_lds[grp * NSLOT + slot] = fmaxf(m_lds[grp * NSLOT + slot], local_max);
                used[slot] = 1;
              }
            } else {
              float* rp = r_buf + cur_g * D + d4 * 4;
              atomicAdd(rp + 0, acc.x); atomicAdd(rp + 1, acc.y);
              atomicAdd(rp + 2, acc.z); atomicAdd(rp + 3, acc.w);
              if (d4 == 0) { atomicAdd(&s_buf[cur_g], sum_ex); atomicMax(&m_enc[cur_g], encf(local_max)); }
            }
          }
          cur_g = g; acc = make_float4(0,0,0,0); sum_ex = 0.f; local_max = -3.4e38f;
        }
        acc.x += ex * f.x; acc.y += ex * f.y; acc.z += ex * f.z; acc.w += ex * f.w;
        if (d4 == 0) { sum_ex += ex; local_max = fmaxf(local_max, dt); }
      }
    }
    // tail flush
    if (cur_g >= 0) {
      int slot = cur_g - gfirst;
      if (slot >= 0 && slot < NSLOT) {
        float4* p = (float4*)&r_lds[((grp * NSLOT + slot) << 6) + (d4 << 2)];
        float4 v = *p;
        v.x += acc.x; v.y += acc.y; v.z += acc.z; v.w += acc.w;
        *p = v;
        if (d4 == 0) {
          s_lds[grp * NSLOT + slot] += sum_ex;
          m_lds[grp * NSLOT + slot] = fmaxf(m_lds[grp * NSLOT + slot], local_max);
          used[slot] = 1;
        }
      } else {
        float* rp = r_buf + cur_g * D + d4 * 4;
        atomicAdd(rp + 0, acc.x); atomicAdd(rp + 1, acc.y);
        atomicAdd(rp + 2, acc.z); atomicAdd(rp + 3, acc.w);
        if (d4 == 0) { atomicAdd(&s_buf[cur_g], sum_ex); atomicMax(&m_enc[cur_g], encf(local_max)); }
      }
    }
    __syncthreads();

    // block-level reduction
    {
      int slot = tid >> 6, dim = tid & 63;
      int g = gfirst + slot;
      if (g < B && used[slot]) {
        float sum = 0.0f;
        #pragma unroll
        for (int q = 0; q < 16; ++q) sum += r_lds[((q * NSLOT + slot) << 6) + dim];
        atomicAdd(&r_buf[g * D + dim], sum);
      }
    }
    if (tid < NSLOT) {
      int g = gfirst + tid;
      if (g < B && used[tid]) {
        float ssum = 0.0f;
        #pragma unroll
        for (int q = 0; q < 16; ++q) ssum += s_lds[q * NSLOT + tid];
        atomicAdd(&s_buf[g], ssum);
      }
    } else if (tid >= 64 && tid < 64 + NSLOT) {
      int slot = tid - 64;
      int g = gfirst + slot;
      if (g < B && used[slot]) {
        float mmax = -3.4e38f;
        #pragma unroll
        for (int q = 0; q < 16; ++q) mmax = fmaxf(mmax, m_lds[q * NSLOT + slot]);
        atomicMax(&m_enc[g], encf(mmax));
      }
    }
    __syncthreads();
    gg.sync();
  }

  // ---------------- MLP (side 0, blocks bx < B) ----------------
  if (side == 0 && bx < B) {
    const int b = bx, t = tid;
    float* x   = r_lds;            // reuse LDS
    float* hh1 = r_lds + 4 * D;
    float* hh2 = r_lds + 4 * D + 32;
    if (t < 128) {
      x[t]       = (t < D) ? h2g[b * D + t]         : r2g[b * D + (t - D)] / s2g[b];
      x[128 + t] = (t < D) ? h2g[B * D + b * D + t] : r2g[B * D + b * D + (t - D)] / s2g[B + b];
    }
    __syncthreads();
    if (t < 32) {
      float acc = b1[t];
      const float* w = W1 + (size_t)t * (4 * D);
      #pragma unroll 8
      for (int k = 0; k < 4 * D; ++k) acc += x[k] * w[k];
      hh1[t] = fmaxf(acc, 0.0f);
    }
    __syncthreads();
    if (t < 16) {
      float acc = b2[t];
      const float* w = W2 + (size_t)t * 32;
      #pragma unroll
      for (int k = 0; k < 32; ++k) acc += hh1[k] * w[k];
      hh2[t] = fmaxf(acc, 0.0f);
    }
    __syncthreads();
    if (t == 0) {
      float acc = b3[0];
      #pragma unroll
      for (int k = 0; k < 16; ++k) acc += hh2[k] * W3[k];
      out[b] = acc;
    }
  }
}

// ---------------- driver ----------------

extern "C" void kernel_launch(void* const* d_in, const int* in_sizes, int n_in,
                              void* d_out, int out_size, void* d_ws, size_t ws_size,
                              hipStream_t stream) {
  const float* feat      = (const float*)d_in[0];
  const float* efeat     = (const float*)d_in[1];
  const int*   edge_dst  = (const int*)d_in[2];
  const int*   node_graph= (const int*)d_in[3];
  const float* node_Wih  = (const float*)d_in[5];
  const float* node_Whh  = (const float*)d_in[6];
  const float* node_bih  = (const float*)d_in[7];
  const float* node_bhh  = (const float*)d_in[8];
  const float* edge_Wih  = (const float*)d_in[9];
  const float* edge_Whh  = (const float*)d_in[10];
  const float* edge_bih  = (const float*)d_in[11];
  const float* edge_bhh  = (const float*)d_in[12];
  const float* W1 = (const float*)d_in[13];
  const float* b1 = (const float*)d_in[14];
  const float* W2 = (const float*)d_in[15];
  const float* b2 = (const float*)d_in[16];
  const float* W3 = (const float*)d_in[17];
  const float* b3 = (const float*)d_in[18];
  float* out = (float*)d_out;

  const int N = in_sizes[0] / D;
  const int E = in_sizes[2];

  // ws layout
  float* ws = (float*)d_ws;
  size_t off = 0;
  float* edge_agg = ws + off; off += (size_t)N * D;       // 25.6 MB
  float* h2       = ws + off; off += 2 * B * D;           // [node|edge] (zeroed)
  float* c2       = ws + off; off += 2 * B * D;           // (zeroed)
  float* s2       = ws + off; off += 2 * B;
  float* r2       = ws + off; off += 2 * B * D;
  float* off2     = ws + off; off += 2 * B;
  unsigned* m2    = (unsigned*)(ws + off); off += 2 * B;
  int* deg        = (int*)(ws + off); off += N;
  int* row_start  = (int*)(ws + off); off += N;
  int* cursor     = (int*)(ws + off); off += N;
  int* blocksum   = (int*)(ws + off); off += 128;
  int* csr        = (int*)(ws + off); off += E + 8;

  hipMemsetAsync(deg, 0, (size_t)N * sizeof(int), stream);
  hipMemsetAsync(h2, 0, (size_t)(4 * B * D) * sizeof(float), stream);  // h2+c2

  // CSR build
  const int nb = (N + SCAN_BS - 1) / SCAN_BS;
  k_deg<<<(E + 255) / 256, 256, 0, stream>>>(edge_dst, deg, E);
  k_scan1<<<nb, SCAN_BS, 0, stream>>>(deg, row_start, blocksum, N);
  k_scan2<<<1, 128, 0, stream>>>(blocksum, nb);
  k_scan3<<<(N + 255) / 256, 256, 0, stream>>>(row_start, blocksum, cursor, N);
  k_fill<<<(E + 255) / 256, 256, 0, stream>>>(edge_dst, cursor, csr, E);

  // gather: one 16-lane group per node, 16 groups per block
  k_gather<<<(N + 15) / 16, 256, 0, stream>>>(efeat, csr, row_start, deg, edge_agg, N);

  // cooperative set2set (both sides) + MLP
  int nchunks = (N + NPB - 1) / NPB;   // 196 blocks/side at N=100K -> co-resident
  void* args[] = {
    (void*)&feat, (void*)&edge_agg, (void*)&node_graph,
    (void*)&h2, (void*)&c2, (void*)&s2, (void*)&r2, (void*)&m2, (void*)&off2,
    (void*)&node_Wih, (void*)&node_Whh, (void*)&node_bih, (void*)&node_bhh,
    (void*)&edge_Wih, (void*)&edge_Whh, (void*)&edge_bih, (void*)&edge_bhh,
    (void*)&W1, (void*)&b1, (void*)&W2, (void*)&b2, (void*)&W3, (void*)&b3,
    (void*)&out, (void*)&N
  };
  hipLaunchCooperativeKernel((void*)k_s2s, dim3(nchunks, 2), dim3(256),
                             args, 0, stream);
}

// Round 8
// 285.197 us; speedup vs baseline: 1.9651x; 1.9651x over previous
//
#include <hip/hip_runtime.h>
#include <math.h>

#define D 64
#define B 64
#define NPB 256      // nodes per att block
#define NSLOT 4
#define SCAN_BS 1024

__device__ __forceinline__ unsigned encf(float x) {
  unsigned u = __float_as_uint(x);
  return (u & 0x80000000u) ? ~u : (u | 0x80000000u);
}
__device__ __forceinline__ float decf(unsigned e) {
  return (e & 0x80000000u) ? __uint_as_float(e ^ 0x80000000u) : __uint_as_float(~e);
}
__device__ __forceinline__ float sigm(float x) { return 1.0f / (1.0f + expf(-x)); }

// ---------------- CSR build ----------------

__global__ void k_deg(const int* __restrict__ edge_dst, int* __restrict__ deg, int E) {
  int i = blockIdx.x * blockDim.x + threadIdx.x;
  if (i < E) atomicAdd(&deg[edge_dst[i]], 1);
}

__global__ void k_scan1(const int* __restrict__ deg, int* __restrict__ row_start,
                        int* __restrict__ blocksum, int N) {
  __shared__ int sm[SCAN_BS];
  int t = threadIdx.x;
  int base = blockIdx.x * SCAN_BS;
  int v = (base + t < N) ? deg[base + t] : 0;
  sm[t] = v;
  __syncthreads();
  for (int ofs = 1; ofs < SCAN_BS; ofs <<= 1) {
    int add = (t >= ofs) ? sm[t - ofs] : 0;
    __syncthreads();
    sm[t] += add;
    __syncthreads();
  }
  if (base + t < N) row_start[base + t] = sm[t] - v;
  if (t == SCAN_BS - 1) blocksum[blockIdx.x] = sm[t];
}

__global__ void k_scan2(int* __restrict__ blocksum, int nb) {
  __shared__ int sm[128];
  int t = threadIdx.x;
  int v = (t < nb) ? blocksum[t] : 0;
  sm[t] = v;
  __syncthreads();
  for (int ofs = 1; ofs < 128; ofs <<= 1) {
    int add = (t >= ofs) ? sm[t - ofs] : 0;
    __syncthreads();
    sm[t] += add;
    __syncthreads();
  }
  if (t < nb) blocksum[t] = sm[t] - v;
}

__global__ void k_scan3(int* __restrict__ row_start, const int* __restrict__ blocksum,
                        int* __restrict__ cursor, int N) {
  int n = blockIdx.x * blockDim.x + threadIdx.x;
  if (n < N) {
    int v = row_start[n] + blocksum[n / SCAN_BS];
    row_start[n] = v;
    cursor[n] = v;
  }
}

__global__ void k_fill(const int* __restrict__ edge_dst, int* __restrict__ cursor,
                       int* __restrict__ csr, int E) {
  int e = blockIdx.x * blockDim.x + threadIdx.x;
  if (e < E) {
    int dst = edge_dst[e];
    int idx = atomicAdd(&cursor[dst], 1);
    csr[idx] = e;
  }
}

// ---------------- shared attention machinery ----------------

struct AttSmem {
  float r_lds[16 * NSLOT * D];   // 16KB
  float s_lds[16 * NSLOT];
  float m_lds[16 * NSLOT];
  float h_lds[NSLOT * D];
  float o_lds[NSLOT];
  int used[NSLOT];
  int sg_first;
};

// one att chunk: base = bx*NPB over F with per-graph state of `side`
__device__ __forceinline__ void att_body(AttSmem* sm, const float* __restrict__ F,
                                         const int* __restrict__ gid,
                                         const float* __restrict__ h,
                                         const float* __restrict__ off,
                                         unsigned* __restrict__ m_enc,
                                         float* __restrict__ s_buf,
                                         float* __restrict__ r_buf,
                                         int N, int bx) {
  const int tid = threadIdx.x;
  const int grp = tid >> 4;
  const int d4  = tid & 15;
  const int base = bx * NPB;

  for (int i = tid; i < 16 * NSLOT * D; i += 256) sm->r_lds[i] = 0.0f;
  if (tid < 16 * NSLOT) { sm->s_lds[tid] = 0.0f; sm->m_lds[tid] = -3.4e38f; }
  if (tid < NSLOT) sm->used[tid] = 0;
  if (tid == 0) sm->sg_first = gid[base];
  __syncthreads();
  const int gfirst = sm->sg_first;
  {
    int slot = tid >> 6, dim = tid & 63;
    int g = gfirst + slot;
    if (g < B) {
      sm->h_lds[tid] = h[g * D + dim];
      if (dim == 0) sm->o_lds[slot] = off[g];
    }
  }
  __syncthreads();

  float4 acc = make_float4(0.f, 0.f, 0.f, 0.f);
  float sum_ex = 0.0f;
  float local_max = -3.4e38f;
  int cur_g = -1;

  for (int itn = 0; itn < NPB / 32; ++itn) {
    int n0 = base + itn * 32 + grp;
    int n1 = n0 + 16;
    bool ok0 = n0 < N, ok1 = n1 < N;
    int g0 = ok0 ? gid[n0] : -1;
    int g1 = ok1 ? gid[n1] : -1;
    float4 f0 = make_float4(0,0,0,0), f1 = make_float4(0,0,0,0);
    float dot0 = 0.f, dot1 = 0.f, ex0 = 0.f, ex1 = 0.f;
    if (ok0) {
      f0 = *(const float4*)(F + (size_t)n0 * D + d4 * 4);
      int s0 = g0 - gfirst;
      float4 hv = (s0 >= 0 && s0 < NSLOT) ? *(const float4*)&sm->h_lds[(s0 << 6) + (d4 << 2)]
                                          : *(const float4*)(h + (size_t)g0 * D + d4 * 4);
      dot0 = f0.x * hv.x + f0.y * hv.y + f0.z * hv.z + f0.w * hv.w;
    }
    if (ok1) {
      f1 = *(const float4*)(F + (size_t)n1 * D + d4 * 4);
      int s1 = g1 - gfirst;
      float4 hv = (s1 >= 0 && s1 < NSLOT) ? *(const float4*)&sm->h_lds[(s1 << 6) + (d4 << 2)]
                                          : *(const float4*)(h + (size_t)g1 * D + d4 * 4);
      dot1 = f1.x * hv.x + f1.y * hv.y + f1.z * hv.z + f1.w * hv.w;
    }
    dot0 += __shfl_xor(dot0, 1); dot1 += __shfl_xor(dot1, 1);
    dot0 += __shfl_xor(dot0, 2); dot1 += __shfl_xor(dot1, 2);
    dot0 += __shfl_xor(dot0, 4); dot1 += __shfl_xor(dot1, 4);
    dot0 += __shfl_xor(dot0, 8); dot1 += __shfl_xor(dot1, 8);
    if (ok0) {
      int s0 = g0 - gfirst;
      ex0 = expf(dot0 - ((s0 >= 0 && s0 < NSLOT) ? sm->o_lds[s0] : off[g0]));
    }
    if (ok1) {
      int s1 = g1 - gfirst;
      ex1 = expf(dot1 - ((s1 >= 0 && s1 < NSLOT) ? sm->o_lds[s1] : off[g1]));
    }

    #pragma unroll
    for (int pair = 0; pair < 2; ++pair) {
      bool ok = pair ? ok1 : ok0;
      int g = pair ? g1 : g0;
      float ex = pair ? ex1 : ex0;
      float dt = pair ? dot1 : dot0;
      float4 f = pair ? f1 : f0;
      if (!ok) continue;
      if (g != cur_g) {
        if (cur_g >= 0) {
          int slot = cur_g - gfirst;
          if (slot >= 0 && slot < NSLOT) {
            float4* p = (float4*)&sm->r_lds[((grp * NSLOT + slot) << 6) + (d4 << 2)];
            float4 v = *p;
            v.x += acc.x; v.y += acc.y; v.z += acc.z; v.w += acc.w;
            *p = v;
            if (d4 == 0) {
              sm->s_lds[grp * NSLOT + slot] += sum_ex;
              sm->m_lds[grp * NSLOT + slot] = fmaxf(sm->m_lds[grp * NSLOT + slot], local_max);
              sm->used[slot] = 1;
            }
          } else {
            float* rp = r_buf + cur_g * D + d4 * 4;
            atomicAdd(rp + 0, acc.x); atomicAdd(rp + 1, acc.y);
            atomicAdd(rp + 2, acc.z); atomicAdd(rp + 3, acc.w);
            if (d4 == 0) { atomicAdd(&s_buf[cur_g], sum_ex); atomicMax(&m_enc[cur_g], encf(local_max)); }
          }
        }
        cur_g = g; acc = make_float4(0,0,0,0); sum_ex = 0.f; local_max = -3.4e38f;
      }
      acc.x += ex * f.x; acc.y += ex * f.y; acc.z += ex * f.z; acc.w += ex * f.w;
      if (d4 == 0) { sum_ex += ex; local_max = fmaxf(local_max, dt); }
    }
  }
  if (cur_g >= 0) {
    int slot = cur_g - gfirst;
    if (slot >= 0 && slot < NSLOT) {
      float4* p = (float4*)&sm->r_lds[((grp * NSLOT + slot) << 6) + (d4 << 2)];
      float4 v = *p;
      v.x += acc.x; v.y += acc.y; v.z += acc.z; v.w += acc.w;
      *p = v;
      if (d4 == 0) {
        sm->s_lds[grp * NSLOT + slot] += sum_ex;
        sm->m_lds[grp * NSLOT + slot] = fmaxf(sm->m_lds[grp * NSLOT + slot], local_max);
        sm->used[slot] = 1;
      }
    } else {
      float* rp = r_buf + cur_g * D + d4 * 4;
      atomicAdd(rp + 0, acc.x); atomicAdd(rp + 1, acc.y);
      atomicAdd(rp + 2, acc.z); atomicAdd(rp + 3, acc.w);
      if (d4 == 0) { atomicAdd(&s_buf[cur_g], sum_ex); atomicMax(&m_enc[cur_g], encf(local_max)); }
    }
  }
  __syncthreads();

  {
    int slot = tid >> 6, dim = tid & 63;
    int g = gfirst + slot;
    if (g < B && sm->used[slot]) {
      float sum = 0.0f;
      #pragma unroll
      for (int q = 0; q < 16; ++q) sum += sm->r_lds[((q * NSLOT + slot) << 6) + dim];
      atomicAdd(&r_buf[g * D + dim], sum);
    }
  }
  if (tid < NSLOT) {
    int g = gfirst + tid;
    if (g < B && sm->used[tid]) {
      float ssum = 0.0f;
      #pragma unroll
      for (int q = 0; q < 16; ++q) ssum += sm->s_lds[q * NSLOT + tid];
      atomicAdd(&s_buf[g], ssum);
    }
  } else if (tid >= 64 && tid < 64 + NSLOT) {
    int slot = tid - 64;
    int g = gfirst + slot;
    if (g < B && sm->used[slot]) {
      float mmax = -3.4e38f;
      #pragma unroll
      for (int q = 0; q < 16; ++q) mmax = fmaxf(mmax, sm->m_lds[q * NSLOT + slot]);
      atomicMax(&m_enc[g], encf(mmax));
    }
  }
}

__device__ __forceinline__ void gather_body(const float* __restrict__ efeat,
                                            const int* __restrict__ csr,
                                            const int* __restrict__ row_start,
                                            const int* __restrict__ deg,
                                            float* __restrict__ edge_agg, int N, int bx) {
  int grp = (bx * 256 + threadIdx.x) >> 4;
  int l16 = threadIdx.x & 15;
  if (grp >= N) return;
  int base = row_start[grp];
  int dg = deg[grp];
  float4 acc = make_float4(0.f, 0.f, 0.f, 0.f);
  for (int i = 0; i < dg; i += 16) {
    int idx[16];
    #pragma unroll
    for (int j = 0; j < 16; ++j) {
      int k = i + j;
      idx[j] = csr[base + (k < dg ? k : dg - 1)];
    }
    #pragma unroll
    for (int j = 0; j < 16; ++j) {
      float4 v = *(const float4*)(efeat + (size_t)idx[j] * D + l16 * 4);
      bool ok = (i + j < dg);
      acc.x += ok ? v.x : 0.0f;
      acc.y += ok ? v.y : 0.0f;
      acc.z += ok ? v.z : 0.0f;
      acc.w += ok ? v.w : 0.0f;
    }
  }
  float inv = 1.0f / fmaxf((float)dg, 1.0f);
  acc.x *= inv; acc.y *= inv; acc.z *= inv; acc.w *= inv;
  *(float4*)(edge_agg + (size_t)grp * D + l16 * 4) = acc;
}

// merged: blocks [0,GB) gather; blocks [GB, GB+att_blocks) att node-side
__global__ void k_gather_att0(int GB, const float* __restrict__ efeat,
                              const int* __restrict__ csr, const int* __restrict__ row_start,
                              const int* __restrict__ deg, float* __restrict__ edge_agg,
                              const float* __restrict__ feat, const int* __restrict__ gid,
                              const float* __restrict__ h2, const float* __restrict__ off2,
                              unsigned* __restrict__ m2, float* __restrict__ s2,
                              float* __restrict__ r2, int N) {
  __shared__ AttSmem sm;
  if ((int)blockIdx.x < GB) {
    gather_body(efeat, csr, row_start, deg, edge_agg, N, blockIdx.x);
  } else {
    att_body(&sm, feat, gid, h2, off2, m2, s2, r2, N, blockIdx.x - GB);
  }
}

// att for side = blockIdx.y + side_base
__global__ void k_att(int side_base, const float* __restrict__ feat,
                      const float* __restrict__ edge_agg, const int* __restrict__ gid,
                      const float* __restrict__ h2, const float* __restrict__ off2,
                      unsigned* __restrict__ m2, float* __restrict__ s2,
                      float* __restrict__ r2, int N) {
  __shared__ AttSmem sm;
  int side = blockIdx.y + side_base;
  att_body(&sm, side ? edge_agg : feat, gid, h2 + side * B * D, off2 + side * B,
           m2 + side * B, s2 + side * B, r2 + side * B * D, N, blockIdx.x);
}

// ---------------- LSTM (per-side first flags; side = blockIdx.y + side_base) --

__global__ void k_lstm(int firstN, int firstE, int side_base,
                       float* __restrict__ h2, float* __restrict__ c2,
                       float* __restrict__ s2, float* __restrict__ r2,
                       unsigned* __restrict__ m2, float* __restrict__ off2,
                       const float* __restrict__ nWih, const float* __restrict__ nWhh,
                       const float* __restrict__ nbih, const float* __restrict__ nbhh,
                       const float* __restrict__ eWih, const float* __restrict__ eWhh,
                       const float* __restrict__ ebih, const float* __restrict__ ebhh) {
  __shared__ float lq[2 * D], lsg[4 * D];
  int side = blockIdx.y + side_base;
  int first = side ? firstE : firstN;
  const float* Wih = side ? eWih : nWih;
  const float* Whh = side ? eWhh : nWhh;
  const float* bih = side ? ebih : nbih;
  const float* bhh = side ? ebhh : nbhh;
  float* h = h2 + side * B * D;
  float* c = c2 + side * B * D;
  float* s_buf = s2 + side * B;
  float* r_buf = r2 + side * B * D;
  unsigned* m_enc = m2 + side * B;
  float* off = off2 + side * B;

  int b = blockIdx.x, j = threadIdx.x;
  if (j < D) {
    lq[j] = h[b * D + j];
  } else if (j < 2 * D) {
    lq[j] = first ? 0.0f : (r_buf[b * D + (j - D)] / s_buf[b]);
  }
  __syncthreads();
  float acc = bih[j] + bhh[j];
  const float* wr = Wih + (size_t)j * (2 * D);
  #pragma unroll 8
  for (int k = 0; k < 2 * D; ++k) acc += lq[k] * wr[k];
  const float* wr2 = Whh + (size_t)j * D;
  #pragma unroll 8
  for (int k = 0; k < D; ++k) acc += lq[k] * wr2[k];
  lsg[j] = acc;
  __syncthreads();
  if (j < D) {
    float ig = sigm(lsg[j]);
    float fg = sigm(lsg[D + j]);
    float gg = tanhf(lsg[2 * D + j]);
    float og = sigm(lsg[3 * D + j]);
    float cn = fg * c[b * D + j] + ig * gg;
    c[b * D + j] = cn;
    h[b * D + j] = og * tanhf(cn);
    r_buf[b * D + j] = 0.0f;
  }
  if (j == D) s_buf[b] = 0.0f;
  if (j == D + 1) {
    off[b] = first ? 0.0f : decf(m_enc[b]);
    m_enc[b] = 0u;
  }
}

// ---------------- MLP ----------------

__global__ void k_mlp(const float* __restrict__ h2, const float* __restrict__ r2,
                      const float* __restrict__ s2,
                      const float* __restrict__ W1, const float* __restrict__ b1,
                      const float* __restrict__ W2, const float* __restrict__ b2,
                      const float* __restrict__ W3, const float* __restrict__ b3,
                      float* __restrict__ out) {
  __shared__ float x[4 * D], h1[32], h2s[16];
  int b = blockIdx.x, t = threadIdx.x;   // 128 threads
  x[t]       = (t < D) ? h2[b * D + t]         : r2[b * D + (t - D)] / s2[b];
  x[128 + t] = (t < D) ? h2[B * D + b * D + t] : r2[B * D + b * D + (t - D)] / s2[B + b];
  __syncthreads();
  if (t < 32) {
    float acc = b1[t];
    const float* w = W1 + (size_t)t * (4 * D);
    #pragma unroll 8
    for (int k = 0; k < 4 * D; ++k) acc += x[k] * w[k];
    h1[t] = fmaxf(acc, 0.0f);
  }
  __syncthreads();
  if (t < 16) {
    float acc = b2[t];
    const float* w = W2 + (size_t)t * 32;
    #pragma unroll
    for (int k = 0; k < 32; ++k) acc += h1[k] * w[k];
    h2s[t] = fmaxf(acc, 0.0f);
  }
  __syncthreads();
  if (t == 0) {
    float acc = b3[0];
    #pragma unroll
    for (int k = 0; k < 16; ++k) acc += h2s[k] * W3[k];
    out[b] = acc;
  }
}

// ---------------- driver ----------------

extern "C" void kernel_launch(void* const* d_in, const int* in_sizes, int n_in,
                              void* d_out, int out_size, void* d_ws, size_t ws_size,
                              hipStream_t stream) {
  const float* feat      = (const float*)d_in[0];
  const float* efeat     = (const float*)d_in[1];
  const int*   edge_dst  = (const int*)d_in[2];
  const int*   node_graph= (const int*)d_in[3];
  const float* node_Wih  = (const float*)d_in[5];
  const float* node_Whh  = (const float*)d_in[6];
  const float* node_bih  = (const float*)d_in[7];
  const float* node_bhh  = (const float*)d_in[8];
  const float* edge_Wih  = (const float*)d_in[9];
  const float* edge_Whh  = (const float*)d_in[10];
  const float* edge_bih  = (const float*)d_in[11];
  const float* edge_bhh  = (const float*)d_in[12];
  const float* W1 = (const float*)d_in[13];
  const float* b1 = (const float*)d_in[14];
  const float* W2 = (const float*)d_in[15];
  const float* b2 = (const float*)d_in[16];
  const float* W3 = (const float*)d_in[17];
  const float* b3 = (const float*)d_in[18];
  float* out = (float*)d_out;

  const int N = in_sizes[0] / D;
  const int E = in_sizes[2];

  // ws layout
  float* ws = (float*)d_ws;
  size_t off = 0;
  float* edge_agg = ws + off; off += (size_t)N * D;
  float* h2       = ws + off; off += 2 * B * D;
  float* c2       = ws + off; off += 2 * B * D;
  float* s2       = ws + off; off += 2 * B;
  float* r2       = ws + off; off += 2 * B * D;
  float* off2     = ws + off; off += 2 * B;
  unsigned* m2    = (unsigned*)(ws + off); off += 2 * B;
  int* deg        = (int*)(ws + off); off += N;
  int* row_start  = (int*)(ws + off); off += N;
  int* cursor     = (int*)(ws + off); off += N;
  int* blocksum   = (int*)(ws + off); off += 128;
  int* csr        = (int*)(ws + off); off += E + 8;

  hipMemsetAsync(deg, 0, (size_t)N * sizeof(int), stream);
  hipMemsetAsync(h2, 0, (size_t)(4 * B * D) * sizeof(float), stream);  // h2+c2

  // CSR build
  const int nb = (N + SCAN_BS - 1) / SCAN_BS;
  k_deg<<<(E + 255) / 256, 256, 0, stream>>>(edge_dst, deg, E);
  k_scan1<<<nb, SCAN_BS, 0, stream>>>(deg, row_start, blocksum, N);
  k_scan2<<<1, 128, 0, stream>>>(blocksum, nb);
  k_scan3<<<(N + 255) / 256, 256, 0, stream>>>(row_start, blocksum, cursor, N);
  k_fill<<<(E + 255) / 256, 256, 0, stream>>>(edge_dst, cursor, csr, E);

  const int att_blocks = (N + NPB - 1) / NPB;
  const int GB = (N + 15) / 16;

  // staggered pipeline: node at iter k, edge at iter k-1
  k_lstm<<<dim3(B, 1), 256, 0, stream>>>(1, 0, 0, h2, c2, s2, r2, m2, off2,
      node_Wih, node_Whh, node_bih, node_bhh, edge_Wih, edge_Whh, edge_bih, edge_bhh);
  k_gather_att0<<<GB + att_blocks, 256, 0, stream>>>(GB, efeat, csr, row_start, deg, edge_agg,
      feat, node_graph, h2, off2, m2, s2, r2, N);
  k_lstm<<<dim3(B, 2), 256, 0, stream>>>(0, 1, 0, h2, c2, s2, r2, m2, off2,
      node_Wih, node_Whh, node_bih, node_bhh, edge_Wih, edge_Whh, edge_bih, edge_bhh);
  k_att<<<dim3(att_blocks, 2), 256, 0, stream>>>(0, feat, edge_agg, node_graph, h2, off2, m2, s2, r2, N);
  k_lstm<<<dim3(B, 2), 256, 0, stream>>>(0, 0, 0, h2, c2, s2, r2, m2, off2,
      node_Wih, node_Whh, node_bih, node_bhh, edge_Wih, edge_Whh, edge_bih, edge_bhh);
  k_att<<<dim3(att_blocks, 2), 256, 0, stream>>>(0, feat, edge_agg, node_graph, h2, off2, m2, s2, r2, N);
  k_lstm<<<dim3(B, 1), 256, 0, stream>>>(0, 0, 1, h2, c2, s2, r2, m2, off2,
      node_Wih, node_Whh, node_bih, node_bhh, edge_Wih, edge_Whh, edge_bih, edge_bhh);
  k_att<<<dim3(att_blocks, 1), 256, 0, stream>>>(1, feat, edge_agg, node_graph, h2, off2, m2, s2, r2, N);

  k_mlp<<<B, 128, 0, stream>>>(h2, r2, s2, W1, b1, W2, b2, W3, b3, out);
}

// Round 9
// 256.750 us; speedup vs baseline: 2.1828x; 1.1108x over previous
//
#include <hip/hip_runtime.h>
#include <math.h>

#define D 64
#define B 64
#define NPB 128      // nodes per att block (smaller => more TLP; flushes are LDS-local)
#define NSLOT 4
#define SCAN_BS 1024

__device__ __forceinline__ unsigned encf(float x) {
  unsigned u = __float_as_uint(x);
  return (u & 0x80000000u) ? ~u : (u | 0x80000000u);
}
__device__ __forceinline__ float decf(unsigned e) {
  return (e & 0x80000000u) ? __uint_as_float(e ^ 0x80000000u) : __uint_as_float(~e);
}
__device__ __forceinline__ float sigm(float x) { return 1.0f / (1.0f + __expf(-x)); }

// ---------------- CSR build ----------------

__global__ void k_deg(const int* __restrict__ edge_dst, int* __restrict__ deg, int E) {
  int i = blockIdx.x * blockDim.x + threadIdx.x;
  if (i < E) atomicAdd(&deg[edge_dst[i]], 1);
}

__global__ void k_scan1(const int* __restrict__ deg, int* __restrict__ row_start,
                        int* __restrict__ blocksum, int N) {
  __shared__ int sm[SCAN_BS];
  int t = threadIdx.x;
  int base = blockIdx.x * SCAN_BS;
  int v = (base + t < N) ? deg[base + t] : 0;
  sm[t] = v;
  __syncthreads();
  for (int ofs = 1; ofs < SCAN_BS; ofs <<= 1) {
    int add = (t >= ofs) ? sm[t - ofs] : 0;
    __syncthreads();
    sm[t] += add;
    __syncthreads();
  }
  if (base + t < N) row_start[base + t] = sm[t] - v;
  if (t == SCAN_BS - 1) blocksum[blockIdx.x] = sm[t];
}

__global__ void k_scan2(int* __restrict__ blocksum, int nb) {
  __shared__ int sm[128];
  int t = threadIdx.x;
  int v = (t < nb) ? blocksum[t] : 0;
  sm[t] = v;
  __syncthreads();
  for (int ofs = 1; ofs < 128; ofs <<= 1) {
    int add = (t >= ofs) ? sm[t - ofs] : 0;
    __syncthreads();
    sm[t] += add;
    __syncthreads();
  }
  if (t < nb) blocksum[t] = sm[t] - v;
}

__global__ void k_scan3(int* __restrict__ row_start, const int* __restrict__ blocksum,
                        int* __restrict__ cursor, int N) {
  int n = blockIdx.x * blockDim.x + threadIdx.x;
  if (n < N) {
    int v = row_start[n] + blocksum[n / SCAN_BS];
    row_start[n] = v;
    cursor[n] = v;
  }
}

__global__ void k_fill(const int* __restrict__ edge_dst, int* __restrict__ cursor,
                       int* __restrict__ csr, int E) {
  int e = blockIdx.x * blockDim.x + threadIdx.x;
  if (e < E) {
    int dst = edge_dst[e];
    int idx = atomicAdd(&cursor[dst], 1);
    csr[idx] = e;
  }
}

// one 16-lane group per node; lane = 4 dims (float4). Unroll 16 -> 64
// outstanding 256B row reads per wave.
__global__ void k_gather(const float* __restrict__ efeat, const int* __restrict__ csr,
                         const int* __restrict__ row_start, const int* __restrict__ deg,
                         float* __restrict__ edge_agg, int N) {
  int grp = (blockIdx.x * blockDim.x + threadIdx.x) >> 4;
  int l16 = threadIdx.x & 15;
  if (grp >= N) return;
  int base = row_start[grp];
  int dg = deg[grp];
  float4 acc = make_float4(0.f, 0.f, 0.f, 0.f);
  for (int i = 0; i < dg; i += 16) {
    int idx[16];
    #pragma unroll
    for (int j = 0; j < 16; ++j) {
      int k = i + j;
      idx[j] = csr[base + (k < dg ? k : dg - 1)];   // clamped: stays in row
    }
    #pragma unroll
    for (int j = 0; j < 16; ++j) {
      float4 v = *(const float4*)(efeat + (size_t)idx[j] * D + l16 * 4);
      bool ok = (i + j < dg);
      acc.x += ok ? v.x : 0.0f;
      acc.y += ok ? v.y : 0.0f;
      acc.z += ok ? v.z : 0.0f;
      acc.w += ok ? v.w : 0.0f;
    }
  }
  float inv = 1.0f / fmaxf((float)dg, 1.0f);
  acc.x *= inv; acc.y *= inv; acc.z *= inv; acc.w *= inv;
  *(float4*)(edge_agg + (size_t)grp * D + l16 * 4) = acc;
}

// ---------------- Set2Set (node & edge fused via blockIdx.y) ----------------

// grid (B, 2), 256 threads; thread j computes gate j of 4D gates.
__global__ void k_lstm2(int first, float* __restrict__ h2, float* __restrict__ c2,
                        float* __restrict__ s2, float* __restrict__ r2,
                        unsigned* __restrict__ m2, float* __restrict__ off2,
                        const float* __restrict__ nWih, const float* __restrict__ nWhh,
                        const float* __restrict__ nbih, const float* __restrict__ nbhh,
                        const float* __restrict__ eWih, const float* __restrict__ eWhh,
                        const float* __restrict__ ebih, const float* __restrict__ ebhh) {
  __shared__ float sq[2 * D], sg[4 * D];
  int side = blockIdx.y;
  const float* Wih = side ? eWih : nWih;
  const float* Whh = side ? eWhh : nWhh;
  const float* bih = side ? ebih : nbih;
  const float* bhh = side ? ebhh : nbhh;
  float* h = h2 + side * B * D;
  float* c = c2 + side * B * D;
  float* s_buf = s2 + side * B;
  float* r_buf = r2 + side * B * D;

  int b = blockIdx.x, j = threadIdx.x;
  if (j < D) {
    sq[j] = h[b * D + j];
  } else if (j < 2 * D) {
    sq[j] = first ? 0.0f : (r_buf[b * D + (j - D)] / s_buf[b]);
  }
  __syncthreads();
  float acc = bih[j] + bhh[j];
  const float* wr = Wih + (size_t)j * (2 * D);
  #pragma unroll 8
  for (int k = 0; k < 2 * D; ++k) acc += sq[k] * wr[k];
  const float* wr2 = Whh + (size_t)j * D;
  #pragma unroll 8
  for (int k = 0; k < D; ++k) acc += sq[k] * wr2[k];
  sg[j] = acc;
  __syncthreads();
  if (j < D) {
    float ig = sigm(sg[j]);
    float fg = sigm(sg[D + j]);
    float gg = tanhf(sg[2 * D + j]);
    float og = sigm(sg[3 * D + j]);
    float cn = fg * c[b * D + j] + ig * gg;
    c[b * D + j] = cn;
    h[b * D + j] = og * tanhf(cn);
    r_buf[b * D + j] = 0.0f;
  }
  if (j == D) s_buf[b] = 0.0f;
  if (j == D + 1) {
    int idx = side * B + b;
    off2[idx] = first ? 0.0f : decf(m2[idx]);   // exact: const offset cancels in alpha
    m2[idx] = 0u;
  }
}

// ONE pass over F per iteration. Per-block LDS reduction (NSLOT graph slots),
// single global-atomic flush per block. grid (ceil(N/NPB), 2), 256 threads.
__global__ void k_att_fused(const float* __restrict__ feat, const float* __restrict__ edge_agg,
                            const int* __restrict__ gid, const float* __restrict__ h2,
                            const float* __restrict__ off2, unsigned* __restrict__ m2,
                            float* __restrict__ s2, float* __restrict__ r2, int N) {
  __shared__ float r_lds[16 * NSLOT * D];   // 16KB
  __shared__ float s_lds[16 * NSLOT];
  __shared__ float m_lds[16 * NSLOT];
  __shared__ float h_lds[NSLOT * D];
  __shared__ float o_lds[NSLOT];
  __shared__ int sg_first;
  __shared__ int used[NSLOT];

  int side = blockIdx.y;
  const float* F = side ? edge_agg : feat;
  const float* h = h2 + side * B * D;
  const float* off = off2 + side * B;
  unsigned* m_enc = m2 + side * B;
  float* s_buf = s2 + side * B;
  float* r_buf = r2 + side * B * D;

  int tid = threadIdx.x;
  int grp = tid >> 4;
  int d4  = tid & 15;
  int base = blockIdx.x * NPB;

  for (int i = tid; i < 16 * NSLOT * D; i += 256) r_lds[i] = 0.0f;
  if (tid < 16 * NSLOT) { s_lds[tid] = 0.0f; m_lds[tid] = -3.4e38f; }
  if (tid < NSLOT) used[tid] = 0;
  if (tid == 0) sg_first = gid[base];
  __syncthreads();
  int gfirst = sg_first;
  {
    int slot = tid >> 6, dim = tid & 63;
    int g = gfirst + slot;
    if (g < B) {
      h_lds[tid] = h[g * D + dim];
      if (dim == 0) o_lds[slot] = off[g];
    }
  }
  __syncthreads();

  float4 acc = make_float4(0.f, 0.f, 0.f, 0.f);
  float sum_ex = 0.0f;
  float local_max = -3.4e38f;
  int cur_g = -1;

  for (int it = 0; it < NPB / 32; ++it) {
    int n0 = base + it * 32 + grp;
    int n1 = n0 + 16;
    bool ok0 = n0 < N, ok1 = n1 < N;
    int g0 = ok0 ? gid[n0] : -1;
    int g1 = ok1 ? gid[n1] : -1;
    float4 f0 = make_float4(0,0,0,0), f1 = make_float4(0,0,0,0);
    float dot0 = 0.f, dot1 = 0.f, ex0 = 0.f, ex1 = 0.f;
    if (ok0) {
      f0 = *(const float4*)(F + (size_t)n0 * D + d4 * 4);
      int s0 = g0 - gfirst;
      float4 hv = (s0 >= 0 && s0 < NSLOT) ? *(const float4*)&h_lds[(s0 << 6) + (d4 << 2)]
                                          : *(const float4*)(h + (size_t)g0 * D + d4 * 4);
      dot0 = f0.x * hv.x + f0.y * hv.y + f0.z * hv.z + f0.w * hv.w;
    }
    if (ok1) {
      f1 = *(const float4*)(F + (size_t)n1 * D + d4 * 4);
      int s1 = g1 - gfirst;
      float4 hv = (s1 >= 0 && s1 < NSLOT) ? *(const float4*)&h_lds[(s1 << 6) + (d4 << 2)]
                                          : *(const float4*)(h + (size_t)g1 * D + d4 * 4);
      dot1 = f1.x * hv.x + f1.y * hv.y + f1.z * hv.z + f1.w * hv.w;
    }
    dot0 += __shfl_xor(dot0, 1); dot1 += __shfl_xor(dot1, 1);
    dot0 += __shfl_xor(dot0, 2); dot1 += __shfl_xor(dot1, 2);
    dot0 += __shfl_xor(dot0, 4); dot1 += __shfl_xor(dot1, 4);
    dot0 += __shfl_xor(dot0, 8); dot1 += __shfl_xor(dot1, 8);
    if (ok0) {
      int s0 = g0 - gfirst;
      ex0 = __expf(dot0 - ((s0 >= 0 && s0 < NSLOT) ? o_lds[s0] : off[g0]));
    }
    if (ok1) {
      int s1 = g1 - gfirst;
      ex1 = __expf(dot1 - ((s1 >= 0 && s1 < NSLOT) ? o_lds[s1] : off[g1]));
    }

    #pragma unroll
    for (int pair = 0; pair < 2; ++pair) {
      bool ok = pair ? ok1 : ok0;
      int g = pair ? g1 : g0;
      float ex = pair ? ex1 : ex0;
      float dt = pair ? dot1 : dot0;
      float4 f = pair ? f1 : f0;
      if (!ok) continue;
      if (g != cur_g) {
        if (cur_g >= 0) {
          int slot = cur_g - gfirst;
          if (slot >= 0 && slot < NSLOT) {
            float4* p = (float4*)&r_lds[((grp * NSLOT + slot) << 6) + (d4 << 2)];
            float4 v = *p;
            v.x += acc.x; v.y += acc.y; v.z += acc.z; v.w += acc.w;
            *p = v;
            if (d4 == 0) {
              s_lds[grp * NSLOT + slot] += sum_ex;
              m_lds[grp * NSLOT + slot] = fmaxf(m_lds[grp * NSLOT + slot], local_max);
              used[slot] = 1;
            }
          } else {
            float* rp = r_buf + cur_g * D + d4 * 4;
            atomicAdd(rp + 0, acc.x); atomicAdd(rp + 1, acc.y);
            atomicAdd(rp + 2, acc.z); atomicAdd(rp + 3, acc.w);
            if (d4 == 0) { atomicAdd(&s_buf[cur_g], sum_ex); atomicMax(&m_enc[cur_g], encf(local_max)); }
          }
        }
        cur_g = g; acc = make_float4(0,0,0,0); sum_ex = 0.f; local_max = -3.4e38f;
      }
      acc.x += ex * f.x; acc.y += ex * f.y; acc.z += ex * f.z; acc.w += ex * f.w;
      if (d4 == 0) { sum_ex += ex; local_max = fmaxf(local_max, dt); }
    }
  }
  // tail flush
  if (cur_g >= 0) {
    int slot = cur_g - gfirst;
    if (slot >= 0 && slot < NSLOT) {
      float4* p = (float4*)&r_lds[((grp * NSLOT + slot) << 6) + (d4 << 2)];
      float4 v = *p;
      v.x += acc.x; v.y += acc.y; v.z += acc.z; v.w += acc.w;
      *p = v;
      if (d4 == 0) {
        s_lds[grp * NSLOT + slot] += sum_ex;
        m_lds[grp * NSLOT + slot] = fmaxf(m_lds[grp * NSLOT + slot], local_max);
        used[slot] = 1;
      }
    } else {
      float* rp = r_buf + cur_g * D + d4 * 4;
      atomicAdd(rp + 0, acc.x); atomicAdd(rp + 1, acc.y);
      atomicAdd(rp + 2, acc.z); atomicAdd(rp + 3, acc.w);
      if (d4 == 0) { atomicAdd(&s_buf[cur_g], sum_ex); atomicMax(&m_enc[cur_g], encf(local_max)); }
    }
  }
  __syncthreads();

  // block-level reduction
  {
    int slot = tid >> 6, dim = tid & 63;
    int g = gfirst + slot;
    if (g < B && used[slot]) {
      float sum = 0.0f;
      #pragma unroll
      for (int q = 0; q < 16; ++q) sum += r_lds[((q * NSLOT + slot) << 6) + dim];
      atomicAdd(&r_buf[g * D + dim], sum);
    }
  }
  if (tid < NSLOT) {
    int g = gfirst + tid;
    if (g < B && used[tid]) {
      float ssum = 0.0f;
      #pragma unroll
      for (int q = 0; q < 16; ++q) ssum += s_lds[q * NSLOT + tid];
      atomicAdd(&s_buf[g], ssum);
    }
  } else if (tid >= 64 && tid < 64 + NSLOT) {
    int slot = tid - 64;
    int g = gfirst + slot;
    if (g < B && used[slot]) {
      float mmax = -3.4e38f;
      #pragma unroll
      for (int q = 0; q < 16; ++q) mmax = fmaxf(mmax, m_lds[q * NSLOT + slot]);
      atomicMax(&m_enc[g], encf(mmax));
    }
  }
}

// out[b] = W3 @ relu(W2 @ relu(W1 @ [h_n, r_n/s_n, h_e, r_e/s_e] + b1) + b2) + b3
__global__ void k_mlp(const float* __restrict__ h2, const float* __restrict__ r2,
                      const float* __restrict__ s2,
                      const float* __restrict__ W1, const float* __restrict__ b1,
                      const float* __restrict__ W2, const float* __restrict__ b2,
                      const float* __restrict__ W3, const float* __restrict__ b3,
                      float* __restrict__ out) {
  __shared__ float x[4 * D], h1[32], h2s[16];
  int b = blockIdx.x, t = threadIdx.x;   // 128 threads
  x[t]       = (t < D) ? h2[b * D + t]         : r2[b * D + (t - D)] / s2[b];
  x[128 + t] = (t < D) ? h2[B * D + b * D + t] : r2[B * D + b * D + (t - D)] / s2[B + b];
  __syncthreads();
  if (t < 32) {
    float acc = b1[t];
    const float* w = W1 + (size_t)t * (4 * D);
    #pragma unroll 8
    for (int k = 0; k < 4 * D; ++k) acc += x[k] * w[k];
    h1[t] = fmaxf(acc, 0.0f);
  }
  __syncthreads();
  if (t < 16) {
    float acc = b2[t];
    const float* w = W2 + (size_t)t * 32;
    #pragma unroll
    for (int k = 0; k < 32; ++k) acc += h1[k] * w[k];
    h2s[t] = fmaxf(acc, 0.0f);
  }
  __syncthreads();
  if (t == 0) {
    float acc = b3[0];
    #pragma unroll
    for (int k = 0; k < 16; ++k) acc += h2s[k] * W3[k];
    out[b] = acc;
  }
}

// ---------------- driver ----------------

extern "C" void kernel_launch(void* const* d_in, const int* in_sizes, int n_in,
                              void* d_out, int out_size, void* d_ws, size_t ws_size,
                              hipStream_t stream) {
  const float* feat      = (const float*)d_in[0];
  const float* efeat     = (const float*)d_in[1];
  const int*   edge_dst  = (const int*)d_in[2];
  const int*   node_graph= (const int*)d_in[3];
  const float* node_Wih  = (const float*)d_in[5];
  const float* node_Whh  = (const float*)d_in[6];
  const float* node_bih  = (const float*)d_in[7];
  const float* node_bhh  = (const float*)d_in[8];
  const float* edge_Wih  = (const float*)d_in[9];
  const float* edge_Whh  = (const float*)d_in[10];
  const float* edge_bih  = (const float*)d_in[11];
  const float* edge_bhh  = (const float*)d_in[12];
  const float* W1 = (const float*)d_in[13];
  const float* b1 = (const float*)d_in[14];
  const float* W2 = (const float*)d_in[15];
  const float* b2 = (const float*)d_in[16];
  const float* W3 = (const float*)d_in[17];
  const float* b3 = (const float*)d_in[18];
  float* out = (float*)d_out;

  const int N = in_sizes[0] / D;
  const int E = in_sizes[2];

  // ws layout
  float* ws = (float*)d_ws;
  size_t off = 0;
  float* edge_agg = ws + off; off += (size_t)N * D;
  float* h2       = ws + off; off += 2 * B * D;
  float* c2       = ws + off; off += 2 * B * D;
  float* s2       = ws + off; off += 2 * B;
  float* r2       = ws + off; off += 2 * B * D;
  float* off2     = ws + off; off += 2 * B;
  unsigned* m2    = (unsigned*)(ws + off); off += 2 * B;
  int* deg        = (int*)(ws + off); off += N;
  int* row_start  = (int*)(ws + off); off += N;
  int* cursor     = (int*)(ws + off); off += N;
  int* blocksum   = (int*)(ws + off); off += 128;
  int* csr        = (int*)(ws + off); off += E + 8;

  hipMemsetAsync(deg, 0, (size_t)N * sizeof(int), stream);
  hipMemsetAsync(h2, 0, (size_t)(4 * B * D) * sizeof(float), stream);  // h2+c2

  // CSR build
  const int nb = (N + SCAN_BS - 1) / SCAN_BS;
  k_deg<<<(E + 255) / 256, 256, 0, stream>>>(edge_dst, deg, E);
  k_scan1<<<nb, SCAN_BS, 0, stream>>>(deg, row_start, blocksum, N);
  k_scan2<<<1, 128, 0, stream>>>(blocksum, nb);
  k_scan3<<<(N + 255) / 256, 256, 0, stream>>>(row_start, blocksum, cursor, N);
  k_fill<<<(E + 255) / 256, 256, 0, stream>>>(edge_dst, cursor, csr, E);

  // gather: one 16-lane group per node, 16 groups per block
  k_gather<<<(N + 15) / 16, 256, 0, stream>>>(efeat, csr, row_start, deg, edge_agg, N);

  const int att_blocks = (N + NPB - 1) / NPB;
  dim3 ga(att_blocks, 2), gb(B, 2);

  for (int it = 0; it < 3; ++it) {
    k_lstm2<<<gb, 256, 0, stream>>>(it == 0 ? 1 : 0, h2, c2, s2, r2, m2, off2,
                                    node_Wih, node_Whh, node_bih, node_bhh,
                                    edge_Wih, edge_Whh, edge_bih, edge_bhh);
    k_att_fused<<<ga, 256, 0, stream>>>(feat, edge_agg, node_graph, h2, off2, m2, s2, r2, N);
  }

  k_mlp<<<B, 128, 0, stream>>>(h2, r2, s2, W1, b1, W2, b2, W3, b3, out);
}